// Round 1
// baseline (117.539 us; speedup 1.0000x reference)
//
#include <hip/hip_runtime.h>
#include <math.h>

// Problem constants: x is (32, 4096, 128) fp32, token_positions = arange(4096).
#define BATCH    32
#define SEQLEN   4096
#define DK       128
#define NQUAD    (DK / 4)              // 32 float4 per row
#define ROWQUADS (SEQLEN * NQUAD)      // 131072 float4 per batch (= 2^17)
#define BPT      8                     // batches processed per thread

#define LOG2_THETA 13.287712379549449f // log2(10000)
#define INV_2PI    0.15915494309189535f

// Clang vector type so __builtin_nontemporal_{load,store} accepts it.
typedef float v4f __attribute__((ext_vector_type(4)));

// Single fused streaming kernel, restructured for memory-level parallelism:
//   phase 1: issue all BPT 16-byte loads (nt) back-to-back  -> 8 KiB in
//            flight per wave; trig computes under the load latency.
//   phase 2: rotate + nt store all BPT results.
// nt hints: zero reuse inside the kernel and the harness's 256 MiB poison
// fill sweeps L3 every iteration, so allocating either stream in L2/L3 is
// pure pollution.
__global__ __launch_bounds__(256) void rope_fused_fast(
    const v4f* __restrict__ x,
    const int* __restrict__ pos,
    v4f*       __restrict__ out)
{
    int t     = blockIdx.x * blockDim.x + threadIdx.x;  // [0, 4 * 131072)
    int pid   = t & (ROWQUADS - 1);                     // (s, j) pair id
    int chunk = t >> 17;                                // which group of 8 batches
    int j     = pid & (NQUAD - 1);                      // quad index within row
    int s     = pid >> 5;                               // seq position

    int base = pid + chunk * (BPT * ROWQUADS);

    // Issue the scalar pos load, then all 8 data loads, BEFORE any trig —
    // the transcendental chain (~100 cyc) runs under the HBM latency.
    int p_i = pos[s];

    v4f v[BPT];
    #pragma unroll
    for (int i = 0; i < BPT; ++i)
        v[i] = __builtin_nontemporal_load(&x[base + i * ROWQUADS]);

    float p = (float)p_i;

    // pair indices i0 = 2j, i1 = 2j+1; exponent = 2*i/DK
    float e0 = (float)j * (1.0f / 32.0f);               // 4j/128
    float e1 = e0 + (2.0f / 128.0f);
    float f0 = __builtin_amdgcn_exp2f(-e0 * LOG2_THETA); // theta^(-e0)
    float f1 = __builtin_amdgcn_exp2f(-e1 * LOG2_THETA);

    // angle in revolutions, explicit fract for valid v_sin/v_cos range
    float r0 = p * f0 * INV_2PI;
    float r1 = p * f1 * INV_2PI;
    r0 = r0 - floorf(r0);
    r1 = r1 - floorf(r1);
    float s0 = __builtin_amdgcn_sinf(r0);   // sin(r * 2*pi)
    float c0 = __builtin_amdgcn_cosf(r0);
    float s1 = __builtin_amdgcn_sinf(r1);
    float c1 = __builtin_amdgcn_cosf(r1);

    #pragma unroll
    for (int i = 0; i < BPT; ++i) {
        v4f o;
        o[0] = v[i][0] * c0 - v[i][1] * s0;
        o[1] = v[i][0] * s0 + v[i][1] * c0;
        o[2] = v[i][2] * c1 - v[i][3] * s1;
        o[3] = v[i][2] * s1 + v[i][3] * c1;
        __builtin_nontemporal_store(o, &out[base + i * ROWQUADS]);
    }
}

extern "C" void kernel_launch(void* const* d_in, const int* in_sizes, int n_in,
                              void* d_out, int out_size, void* d_ws, size_t ws_size,
                              hipStream_t stream) {
    const float* x   = (const float*)d_in[0];
    const int*   pos = (const int*)d_in[1];
    float*       out = (float*)d_out;

    // 524288 threads = 2048 blocks x 256; exact, no tail.
    const int nthreads = (BATCH / BPT) * ROWQUADS;
    dim3 block(256), grid(nthreads / 256);
    rope_fused_fast<<<grid, block, 0, stream>>>((const v4f*)x, pos, (v4f*)out);
}

// Round 2
// 112.600 us; speedup vs baseline: 1.0439x; 1.0439x over previous
//
#include <hip/hip_runtime.h>
#include <math.h>

// Problem constants: x is (32, 4096, 128) fp32, token_positions = arange(4096).
#define BATCH    32
#define SEQLEN   4096
#define DK       128
#define NQUAD    (DK / 4)              // 32 float4 per row
#define ROWQUADS (SEQLEN * NQUAD)      // 131072 float4 per batch (= 2^17)
#define BPT      8                     // batches processed per thread

#define LOG2_THETA 13.287712379549449f // log2(10000)
#define INV_2PI    0.15915494309189535f

typedef float v4f __attribute__((ext_vector_type(4)));

// Fused streaming kernel. Round-1 post-mortem: `nt` hints on load/store cost
// +4 µs (the harness fills hit 6.5 TB/s through the normal cached path, so
// L2 write-allocate is how peak write BW is achieved on gfx950 — do not
// bypass it). This version keeps the explicit load-first phase (guaranteed
// MLP=8: 8 KiB in flight per wave, trig hidden under HBM latency) with
// plain cached loads/stores.
__global__ __launch_bounds__(256) void rope_fused_fast(
    const v4f* __restrict__ x,
    const int* __restrict__ pos,
    v4f*       __restrict__ out)
{
    int t     = blockIdx.x * blockDim.x + threadIdx.x;  // [0, 4 * 131072)
    int pid   = t & (ROWQUADS - 1);                     // (s, j) pair id
    int chunk = t >> 17;                                // which group of 8 batches
    int j     = pid & (NQUAD - 1);                      // quad index within row
    int s     = pid >> 5;                               // seq position

    int base = pid + chunk * (BPT * ROWQUADS);

    // Scalar pos load + all 8 data loads issued before any trig.
    int p_i = pos[s];

    v4f v[BPT];
    #pragma unroll
    for (int i = 0; i < BPT; ++i)
        v[i] = x[base + i * ROWQUADS];

    float p = (float)p_i;

    // pair indices i0 = 2j, i1 = 2j+1; exponent = 2*i/DK
    float e0 = (float)j * (1.0f / 32.0f);               // 4j/128
    float e1 = e0 + (2.0f / 128.0f);
    float f0 = __builtin_amdgcn_exp2f(-e0 * LOG2_THETA); // theta^(-e0)
    float f1 = __builtin_amdgcn_exp2f(-e1 * LOG2_THETA);

    // angle in revolutions, explicit fract for valid v_sin/v_cos range
    float r0 = p * f0 * INV_2PI;
    float r1 = p * f1 * INV_2PI;
    r0 = r0 - floorf(r0);
    r1 = r1 - floorf(r1);
    float s0 = __builtin_amdgcn_sinf(r0);   // sin(r * 2*pi)
    float c0 = __builtin_amdgcn_cosf(r0);
    float s1 = __builtin_amdgcn_sinf(r1);
    float c1 = __builtin_amdgcn_cosf(r1);

    #pragma unroll
    for (int i = 0; i < BPT; ++i) {
        v4f o;
        o[0] = v[i][0] * c0 - v[i][1] * s0;
        o[1] = v[i][0] * s0 + v[i][1] * c0;
        o[2] = v[i][2] * c1 - v[i][3] * s1;
        o[3] = v[i][2] * s1 + v[i][3] * c1;
        out[base + i * ROWQUADS] = o;
    }
}

extern "C" void kernel_launch(void* const* d_in, const int* in_sizes, int n_in,
                              void* d_out, int out_size, void* d_ws, size_t ws_size,
                              hipStream_t stream) {
    const float* x   = (const float*)d_in[0];
    const int*   pos = (const int*)d_in[1];
    float*       out = (float*)d_out;

    // 524288 threads = 2048 blocks x 256; exact, no tail.
    const int nthreads = (BATCH / BPT) * ROWQUADS;
    dim3 block(256), grid(nthreads / 256);
    rope_fused_fast<<<grid, block, 0, stream>>>((const v4f*)x, pos, (v4f*)out);
}